// Round 4
// baseline (1439.090 us; speedup 1.0000x reference)
//
#include <hip/hip_runtime.h>
#include <stdint.h>

// ---------------- types ----------------
typedef __attribute__((ext_vector_type(8))) short bf16x8;   // 8 x bf16 = 4 VGPRs
typedef __attribute__((ext_vector_type(4))) short s16x4;    // 4 x bf16 = 8B
typedef __attribute__((ext_vector_type(4))) float f32x4;
typedef __attribute__((ext_vector_type(4))) unsigned u32x4;

#define AS1 __attribute__((address_space(1)))
#define AS3 __attribute__((address_space(3)))

static __device__ __forceinline__ void gload_lds16(const void* g, void* l) {
  __builtin_amdgcn_global_load_lds((const AS1 unsigned int*)g,
                                   (AS3 unsigned int*)l, 16, 0, 0);
}

// round-to-nearest-even f32 -> bf16 bits
static __device__ __forceinline__ short f2bs(float f) {
  unsigned u = __builtin_bit_cast(unsigned, f);
  unsigned r = (u + 0x7fffu + ((u >> 16) & 1u)) >> 16;
  return (short)r;
}
static __device__ __forceinline__ float bs2f(short s) {
  unsigned u = ((unsigned)(unsigned short)s) << 16;
  return __builtin_bit_cast(float, u);
}

static __device__ __forceinline__ float sigmoid_f(float x) {
  return 1.0f / (1.0f + __expf(-x));
}
static __device__ __forceinline__ float tanh_f(float x) {
  float ax = fabsf(x);
  float e  = __expf(-2.0f * ax);
  float t  = (1.0f - e) / (1.0f + e);
  return copysignf(t, x);
}

static __device__ __forceinline__ unsigned stale8(u32x4 a, u32x4 b, unsigned want) {
  return ((a[0] ^ want) | (a[1] ^ want) | (a[2] ^ want) | (a[3] ^ want) |
          (b[0] ^ want) | (b[1] ^ want) | (b[2] ^ want) | (b[3] ^ want)) & 0xffffu;
}

// constants
#define BATCH 256
#define HID   512
#define STEPS 256
#define G3    1536   // 3*HID

// ---------------- fp32 -> bf16 convert (weights) ----------------
__global__ __launch_bounds__(256) void convert_kernel(const float* __restrict__ src,
                                                      short* __restrict__ dst, int n4) {
  int i = blockIdx.x * 256 + threadIdx.x;
  if (i < n4) {
    float4 v = *(const float4*)(src + (size_t)i * 4);
    s16x4 o;
    o[0] = f2bs(v.x); o[1] = f2bs(v.y); o[2] = f2bs(v.z); o[3] = f2bs(v.w);
    *(s16x4*)(dst + (size_t)i * 4) = o;
  }
}

// ---------------- x[b][i][s] f32  ->  xT[s][b][i] bf16 ----------------
__global__ __launch_bounds__(256) void transpose_kernel(const float* __restrict__ x,
                                                        short* __restrict__ xT) {
  int bx = blockIdx.x;
  int st = bx & 7, it = (bx >> 3) & 15, b = bx >> 7;
  int s0 = st * 32, i0 = it * 32;
  int tid = threadIdx.x;
  __shared__ float tile[32][33];
  int il = tid >> 3, s4 = (tid & 7) * 4;
  float4 v = *(const float4*)(x + (size_t)b * 131072 + (size_t)(i0 + il) * 256 + s0 + s4);
  tile[il][s4 + 0] = v.x; tile[il][s4 + 1] = v.y;
  tile[il][s4 + 2] = v.z; tile[il][s4 + 3] = v.w;
  __syncthreads();
  int sl = tid >> 3, iv = (tid & 7) * 4;
  s16x4 o;
  o[0] = f2bs(tile[iv + 0][sl]); o[1] = f2bs(tile[iv + 1][sl]);
  o[2] = f2bs(tile[iv + 2][sl]); o[3] = f2bs(tile[iv + 3][sl]);
  *(s16x4*)(xT + (size_t)(s0 + sl) * 131072 + (size_t)b * 512 + i0 + iv) = o;
}

// ---------------- phase 1: gi[m][g] = xT[m] . W_ih[g] + bias_ih[g] (bf16 out) ----
__global__ __launch_bounds__(256) void phase1_kernel(const short* __restrict__ A,
                                                     const short* __restrict__ B,
                                                     const float* __restrict__ bias,
                                                     short* __restrict__ out, int M) {
  int MT = M >> 7;
  int bx = blockIdx.x;
  int mt = bx % MT, nt = bx / MT;
  int m0 = mt * 128, n0 = nt * 128;
  int tid = threadIdx.x, w = tid >> 6, lane = tid & 63;
  int lm = lane & 15, q = lane >> 4;
  int wm = w & 1, wn = w >> 1;
  __shared__ short As[128 * 32];
  __shared__ short Bs[128 * 32];
  f32x4 acc[4][4] = {};
  int srow = lane >> 2;
  int scol = (lane & 3) * 8;

  for (int kt = 0; kt < 16; ++kt) {
#pragma unroll
    for (int i2 = 0; i2 < 2; ++i2) {
      int i = w * 2 + i2;
      int row = i * 16 + srow;
      gload_lds16(A + (size_t)(m0 + row) * 512 + kt * 32 + scol, As + i * 512);
      gload_lds16(B + (size_t)(n0 + row) * 512 + kt * 32 + scol, Bs + i * 512);
    }
    __syncthreads();
    bf16x8 av[4], bv[4];
#pragma unroll
    for (int f = 0; f < 4; ++f) {
      av[f] = *(const bf16x8*)(As + (wm * 64 + f * 16 + lm) * 32 + q * 8);
      bv[f] = *(const bf16x8*)(Bs + (wn * 64 + f * 16 + lm) * 32 + q * 8);
    }
#pragma unroll
    for (int fm = 0; fm < 4; ++fm)
#pragma unroll
      for (int fn = 0; fn < 4; ++fn)
        acc[fm][fn] = __builtin_amdgcn_mfma_f32_16x16x32_bf16(av[fm], bv[fn], acc[fm][fn], 0, 0, 0);
    __syncthreads();
  }
#pragma unroll
  for (int fn = 0; fn < 4; ++fn) {
    int g = n0 + wn * 64 + fn * 16 + lm;
    float bi = bias[g];
#pragma unroll
    for (int fm = 0; fm < 4; ++fm) {
      int rb = m0 + wm * 64 + fm * 16 + q * 4;
#pragma unroll
      for (int r = 0; r < 4; ++r)
        out[(size_t)(rb + r) * G3 + g] = f2bs(acc[fm][fn][r] + bi);
    }
  }
}

// ---------------- phase 2: persistent GRU scan (4-block groups) --------------
// 16 groups (16 batch rows each) x 4 blocks per group; each block owns 128
// h-cols (3x128 = 384 W_hh rows, held in 192 VGPR/thread across 512 threads).
// Tagged-dword publish protocol as R1: dword = {bf16 h << 16 | step tag};
// dword stores are single-copy atomic so value+tag never tear.
// Poll/stash shapes are byte-identical to R1's proven pattern: lane i reads
// contiguous 16B at tid*16 (+8KB chunk stride) -> fully coalesced; retry is
// whole-bundle with s_sleep(1) pacing, bounded (wrong beats hang).
// Why 4-block groups: per-step finish = max over peers of (detect+compute);
// max-of-4 skew << max-of-16, and poll LLC traffic drops 4x (64 x 32KB vs
// 256 x 32KB per round) -> cheaper, faster detect rounds.
// Safety induction (unchanged from R1, group-local): publishes of tag t+1
// happen only after the barrier that follows all waves' polls of t, so any
// visible tag-t word implies that block passed poll(t-1) entirely; overwrite
// of parity 1-p at step t is safe because poll(t) passing implies all peers
// consumed parity 1-p (their poll(t-1)) already.
__global__ __launch_bounds__(512, 2) void scan_kernel(const short* __restrict__ gi,
                                                      const short* __restrict__ Whh,
                                                      const float* __restrict__ bias_hh,
                                                      unsigned* __restrict__ hbuf,
                                                      float* __restrict__ hmaster,
                                                      int CH, int step_base, int first) {
  int bid = blockIdx.x;                 // 64 blocks
  int xcd = bid & 7, slot = bid >> 3;
  int j = slot & 3;                     // block-in-group: 128-col slice
  int group = xcd + 8 * (slot >> 2);    // 16 groups, peers share an XCD-ish
  int tid = threadIdx.x;                // 512 threads = 8 waves
  int w = tid >> 6, lane = tid & 63;
  int lm = lane & 15, q = lane >> 4;
  int grow = group * 16;

  __shared__ short h_lds[16 * 520];     // full group h, padded rows 512+8
  __shared__ float gh_lds[16][388];     // 384 gate-cols + pad
  __shared__ float h_loc[2048];         // [16 row][128 col] fp32 state slice
  __shared__ float bhh[384];

  // W_hh fragments: wave w owns N-tile w of EACH gate (3 tiles x 16 K-steps
  // = 48 bf16x8 = 192 VGPR). Whh row = g*512 + j*128 + w*16 + lm.
  bf16x8 Wf[3][16];
#pragma unroll
  for (int g = 0; g < 3; ++g)
#pragma unroll
    for (int kt = 0; kt < 16; ++kt)
      Wf[g][kt] = *(const bf16x8*)(Whh + (size_t)(g * 512 + j * 128 + w * 16 + lm) * 512 + kt * 32 + q * 8);

  if (tid < 384) bhh[tid] = bias_hh[(tid >> 7) * 512 + j * 128 + (tid & 127)];
#pragma unroll
  for (int u = 0; u < 4; ++u) {
    int idx = tid + u * 512;
    int r = idx >> 7, cc = idx & 127;
    h_loc[idx] = first ? 0.0f : hmaster[(size_t)(grow + r) * 512 + j * 128 + cc];
  }
  __syncthreads();

  // per-thread gi pointers: 4 elements per thread per gate, bf16
  const short* gp[4];
#pragma unroll
  for (int u = 0; u < 4; ++u) {
    int idx = tid + u * 512;
    gp[u] = gi + (size_t)(grow + (idx >> 7)) * G3 + j * 128 + (idx & 127);
  }
  const size_t gstride = (size_t)256 * G3;
  short pgr[4], pgz[4], pgn[4];
#pragma unroll
  for (int u = 0; u < 4; ++u) { pgr[u] = gp[u][0]; pgz[u] = gp[u][512]; pgn[u] = gp[u][1024]; }

  unsigned* grp = hbuf + (size_t)group * 8192;
  // poll geometry: 512 threads x 4 chunks x 16B = 32KB (whole group h).
  // chunk c: byte tid*16 + c*8192 -> row = (tid>>7)+4c, col = (tid&127)*4
  unsigned o0 = (unsigned)tid * 16u;
  short* lp = h_lds + (tid >> 7) * 520 + (tid & 127) * 4;  // +c*2080 shorts

  for (int t = 0; t < CH; ++t) {
    int gstep = step_base + t;
    int p = gstep & 1;
    const unsigned* src = grp + (size_t)p * 131072;
    unsigned want = (unsigned)gstep & 0xffffu;

    // ---- poll: bulk 4-load, whole-bundle retry with s_sleep pacing.
    // waitcnt INSIDE the asm so the tag check can't be hoisted above it.
    u32x4 v0, v1, v2, v3;
    int spin = 0;
    for (;;) {
      asm volatile(
          "global_load_dwordx4 %0, %4, %8 sc0 sc1\n\t"
          "global_load_dwordx4 %1, %5, %8 sc0 sc1\n\t"
          "global_load_dwordx4 %2, %6, %8 sc0 sc1\n\t"
          "global_load_dwordx4 %3, %7, %8 sc0 sc1\n\t"
          "s_waitcnt vmcnt(0)"
          : "=&v"(v0), "=&v"(v1), "=&v"(v2), "=&v"(v3)
          : "v"(o0), "v"(o0 + 8192u), "v"(o0 + 16384u), "v"(o0 + 24576u),
            "s"(src)
          : "memory");
      unsigned d = stale8(v0, v1, want) | stale8(v2, v3, want);
      if (d == 0u || ++spin > (1 << 15)) break;
      __builtin_amdgcn_s_sleep(1);
    }

    // stash fresh h (strip tags) straight into the MFMA staging layout
#define STASH(vv, c)                                                         \
    {                                                                        \
      s16x4 o_;                                                              \
      o_[0] = (short)(vv[0] >> 16); o_[1] = (short)(vv[1] >> 16);            \
      o_[2] = (short)(vv[2] >> 16); o_[3] = (short)(vv[3] >> 16);            \
      *(s16x4*)(lp + (c) * 2080) = o_;                                       \
    }
    STASH(v0, 0) STASH(v1, 1) STASH(v2, 2) STASH(v3, 3)
#undef STASH

    // consume current gi prefetch; issue next step's (hides under MFMA)
    float cgr[4], cgz[4], cgn[4];
#pragma unroll
    for (int u = 0; u < 4; ++u) { cgr[u] = bs2f(pgr[u]); cgz[u] = bs2f(pgz[u]); cgn[u] = bs2f(pgn[u]); }
    {
      size_t o = (size_t)((t + 1 < CH) ? (t + 1) : t) * gstride;
#pragma unroll
      for (int u = 0; u < 4; ++u) {
        pgr[u] = gp[u][o]; pgz[u] = gp[u][o + 512]; pgn[u] = gp[u][o + 1024];
      }
    }
    __syncthreads();

    // MFMA: each wave computes 16 batch-rows x 48 gate-cols (3 tiles),
    // 3 independent acc chains over K=512.
    {
      f32x4 a0 = {0.f,0.f,0.f,0.f}, a1 = {0.f,0.f,0.f,0.f}, a2 = {0.f,0.f,0.f,0.f};
#pragma unroll
      for (int kt = 0; kt < 16; ++kt) {
        bf16x8 a = *(const bf16x8*)(h_lds + lm * 520 + kt * 32 + q * 8);
        a0 = __builtin_amdgcn_mfma_f32_16x16x32_bf16(a, Wf[0][kt], a0, 0, 0, 0);
        a1 = __builtin_amdgcn_mfma_f32_16x16x32_bf16(a, Wf[1][kt], a1, 0, 0, 0);
        a2 = __builtin_amdgcn_mfma_f32_16x16x32_bf16(a, Wf[2][kt], a2, 0, 0, 0);
      }
#pragma unroll
      for (int r = 0; r < 4; ++r) {
        gh_lds[q * 4 + r][w * 16 + lm]       = a0[r];
        gh_lds[q * 4 + r][128 + w * 16 + lm] = a1[r];
        gh_lds[q * 4 + r][256 + w * 16 + lm] = a2[r];
      }
    }
    __syncthreads();

    // elementwise GRU cell + tagged publish (own values only; h_lds/gh_lds
    // hazards are covered by the barriers bracketing the next iteration)
    unsigned tagp = (unsigned)(gstep + 1);
    unsigned* dstb = grp + (size_t)(1 - p) * 131072;
#pragma unroll
    for (int u = 0; u < 4; ++u) {
      int idx = tid + u * 512;
      int row = idx >> 7, col = idx & 127;
      float hr = gh_lds[row][col]       + bhh[col];
      float hz = gh_lds[row][128 + col] + bhh[128 + col];
      float hn = gh_lds[row][256 + col] + bhh[256 + col];
      float rr = sigmoid_f(cgr[u] + hr);
      float zz = sigmoid_f(cgz[u] + hz);
      float nn = tanh_f(cgn[u] + rr * hn);
      float hv = (1.0f - zz) * nn + zz * h_loc[idx];
      h_loc[idx] = hv;
      unsigned val = (((unsigned)(unsigned short)f2bs(hv)) << 16) | tagp;
      unsigned* dp = dstb + row * 512 + j * 128 + col;
      asm volatile("global_store_dword %0, %1, off sc0 sc1" :: "v"(dp), "v"(val) : "memory");
    }
  }

  // write fp32 state back (d_out doubles as h_master across chunk launches)
#pragma unroll
  for (int u = 0; u < 4; ++u) {
    int idx = tid + u * 512;
    int r = idx >> 7, cc = idx & 127;
    hmaster[(size_t)(grow + r) * 512 + j * 128 + cc] = h_loc[idx];
  }
}

// ---------------- host ----------------
extern "C" void kernel_launch(void* const* d_in, const int* in_sizes, int n_in,
                              void* d_out, int out_size, void* d_ws, size_t ws_size,
                              hipStream_t stream) {
  const float* x   = (const float*)d_in[0];
  const float* Wih = (const float*)d_in[1];
  const float* Whh = (const float*)d_in[2];
  const float* bih = (const float*)d_in[3];
  const float* bhh = (const float*)d_in[4];
  float* out = (float*)d_out;
  char* ws = (char*)d_ws;

  const size_t XT_BYTES   = (size_t)256 * 256 * 512 * 2;  // 64 MiB
  const size_t W_BYTES    = (size_t)1536 * 512 * 2;       // 1.5 MiB
  const size_t HBUF_BYTES = (size_t)2 * 256 * 512 * 4;    // 1 MiB (tagged dwords)
  const size_t FIXED = XT_BYTES + 2 * W_BYTES + HBUF_BYTES + 4096;

  int CH = 256;
  while (CH > 4 && FIXED + (size_t)CH * 256 * G3 * 2 > ws_size) CH >>= 1;

  size_t off = 0;
  short* gi = (short*)(ws + off);          off += (size_t)CH * 256 * G3 * 2;
  short* xT = (short*)(ws + off);          off += XT_BYTES;
  short* WihB = (short*)(ws + off);        off += W_BYTES;
  short* WhhB = (short*)(ws + off);        off += W_BYTES;
  unsigned* hbuf = (unsigned*)(ws + off);

  hipMemsetAsync(hbuf, 0, HBUF_BYTES, stream);

  convert_kernel<<<768, 256, 0, stream>>>(Wih, WihB, 196608);
  convert_kernel<<<768, 256, 0, stream>>>(Whh, WhhB, 196608);
  transpose_kernel<<<32768, 256, 0, stream>>>(x, xT);

  int nch = 256 / CH;
  for (int c = 0; c < nch; ++c) {
    int M = CH * 256;
    phase1_kernel<<<(M / 128) * 12, 256, 0, stream>>>(
        xT + (size_t)c * CH * 256 * 512, WihB, bih, gi, M);
    scan_kernel<<<64, 512, 0, stream>>>(gi, WhhB, bhh, hbuf, out,
                                        CH, c * CH, c == 0 ? 1 : 0);
  }
}

// Round 6
// 881.503 us; speedup vs baseline: 1.6325x; 1.6325x over previous
//
#include <hip/hip_runtime.h>
#include <stdint.h>

// ---------------- types ----------------
typedef __attribute__((ext_vector_type(8))) short bf16x8;   // 8 x bf16 = 4 VGPRs
typedef __attribute__((ext_vector_type(4))) short s16x4;    // 4 x bf16 = 8B
typedef __attribute__((ext_vector_type(4))) float f32x4;
typedef __attribute__((ext_vector_type(4))) unsigned u32x4;

#define AS1 __attribute__((address_space(1)))
#define AS3 __attribute__((address_space(3)))

static __device__ __forceinline__ void gload_lds16(const void* g, void* l) {
  __builtin_amdgcn_global_load_lds((const AS1 unsigned int*)g,
                                   (AS3 unsigned int*)l, 16, 0, 0);
}

// round-to-nearest-even f32 -> bf16 bits
static __device__ __forceinline__ short f2bs(float f) {
  unsigned u = __builtin_bit_cast(unsigned, f);
  unsigned r = (u + 0x7fffu + ((u >> 16) & 1u)) >> 16;
  return (short)r;
}
static __device__ __forceinline__ float bs2f(short s) {
  unsigned u = ((unsigned)(unsigned short)s) << 16;
  return __builtin_bit_cast(float, u);
}

static __device__ __forceinline__ float sigmoid_f(float x) {
  return 1.0f / (1.0f + __expf(-x));
}
static __device__ __forceinline__ float tanh_f(float x) {
  float ax = fabsf(x);
  float e  = __expf(-2.0f * ax);
  float t  = (1.0f - e) / (1.0f + e);
  return copysignf(t, x);
}

// constants
#define BATCH 256
#define HID   512
#define STEPS 256
#define G3    1536   // 3*HID

// ---------------- fp32 -> bf16 convert (weights) ----------------
__global__ __launch_bounds__(256) void convert_kernel(const float* __restrict__ src,
                                                      short* __restrict__ dst, int n4) {
  int i = blockIdx.x * 256 + threadIdx.x;
  if (i < n4) {
    float4 v = *(const float4*)(src + (size_t)i * 4);
    s16x4 o;
    o[0] = f2bs(v.x); o[1] = f2bs(v.y); o[2] = f2bs(v.z); o[3] = f2bs(v.w);
    *(s16x4*)(dst + (size_t)i * 4) = o;
  }
}

// ---------------- x[b][i][s] f32  ->  xT[s][b][i] bf16 ----------------
__global__ __launch_bounds__(256) void transpose_kernel(const float* __restrict__ x,
                                                        short* __restrict__ xT) {
  int bx = blockIdx.x;
  int st = bx & 7, it = (bx >> 3) & 15, b = bx >> 7;
  int s0 = st * 32, i0 = it * 32;
  int tid = threadIdx.x;
  __shared__ float tile[32][33];
  int il = tid >> 3, s4 = (tid & 7) * 4;
  float4 v = *(const float4*)(x + (size_t)b * 131072 + (size_t)(i0 + il) * 256 + s0 + s4);
  tile[il][s4 + 0] = v.x; tile[il][s4 + 1] = v.y;
  tile[il][s4 + 2] = v.z; tile[il][s4 + 3] = v.w;
  __syncthreads();
  int sl = tid >> 3, iv = (tid & 7) * 4;
  s16x4 o;
  o[0] = f2bs(tile[iv + 0][sl]); o[1] = f2bs(tile[iv + 1][sl]);
  o[2] = f2bs(tile[iv + 2][sl]); o[3] = f2bs(tile[iv + 3][sl]);
  *(s16x4*)(xT + (size_t)(s0 + sl) * 131072 + (size_t)b * 512 + i0 + iv) = o;
}

// ---------------- phase 1: gi[m][g] = xT[m] . W_ih[g] + bias_ih[g] (bf16 out) ----
__global__ __launch_bounds__(256) void phase1_kernel(const short* __restrict__ A,
                                                     const short* __restrict__ B,
                                                     const float* __restrict__ bias,
                                                     short* __restrict__ out, int M) {
  int MT = M >> 7;
  int bx = blockIdx.x;
  int mt = bx % MT, nt = bx / MT;
  int m0 = mt * 128, n0 = nt * 128;
  int tid = threadIdx.x, w = tid >> 6, lane = tid & 63;
  int lm = lane & 15, q = lane >> 4;
  int wm = w & 1, wn = w >> 1;
  __shared__ short As[128 * 32];
  __shared__ short Bs[128 * 32];
  f32x4 acc[4][4] = {};
  int srow = lane >> 2;
  int scol = (lane & 3) * 8;

  for (int kt = 0; kt < 16; ++kt) {
#pragma unroll
    for (int i2 = 0; i2 < 2; ++i2) {
      int i = w * 2 + i2;
      int row = i * 16 + srow;
      gload_lds16(A + (size_t)(m0 + row) * 512 + kt * 32 + scol, As + i * 512);
      gload_lds16(B + (size_t)(n0 + row) * 512 + kt * 32 + scol, Bs + i * 512);
    }
    __syncthreads();
    bf16x8 av[4], bv[4];
#pragma unroll
    for (int f = 0; f < 4; ++f) {
      av[f] = *(const bf16x8*)(As + (wm * 64 + f * 16 + lm) * 32 + q * 8);
      bv[f] = *(const bf16x8*)(Bs + (wn * 64 + f * 16 + lm) * 32 + q * 8);
    }
#pragma unroll
    for (int fm = 0; fm < 4; ++fm)
#pragma unroll
      for (int fn = 0; fn < 4; ++fn)
        acc[fm][fn] = __builtin_amdgcn_mfma_f32_16x16x32_bf16(av[fm], bv[fn], acc[fm][fn], 0, 0, 0);
    __syncthreads();
  }
#pragma unroll
  for (int fn = 0; fn < 4; ++fn) {
    int g = n0 + wn * 64 + fn * 16 + lm;
    float bi = bias[g];
#pragma unroll
    for (int fm = 0; fm < 4; ++fm) {
      int rb = m0 + wm * 64 + fm * 16 + q * 4;
#pragma unroll
      for (int r = 0; r < 4; ++r)
        out[(size_t)(rb + r) * G3 + g] = f2bs(acc[fm][fn][r] + bi);
    }
  }
}

// ---------------- phase 2: persistent GRU scan ----------------
// EXACT R1 structure (measured 552us scan) with ONE isolated change:
// RAW BARRIERS. __syncthreads() emits "s_waitcnt vmcnt(0) lgkmcnt(0);
// s_barrier", which serializes the residual HBM latency of the 6 gi-prefetch
// loads (issued ~200ns before barrier #1) into every step. The raw form
// "s_waitcnt lgkmcnt(0); s_barrier" preserves every cross-wave dependency
// these barriers protect (all are LDS: h_lds stash -> MFMA reads, gh_lds
// writes -> cell reads; DS ops are counted by lgkmcnt) while letting gi
// prefetch and publish stores ride across and retire under compute. The
// poll's internal vmcnt(0) remains the per-step VMEM convergence point,
// ~1us after prefetch issue (free by then).
// sched_barrier(0) after each raw barrier pins compiler code motion (rule-18
// hygiene for inline-asm waitcnt).
// Tagged-dword publish protocol unchanged: dword = {bf16 h << 16 | step tag};
// dword stores are single-copy atomic so value+tag never tear. Safety
// induction unchanged: publishes of tag t+1 happen only after the barrier
// that follows all waves' polls of t, so any visible tag-t+2 word implies
// every block passed poll(t); parity double buffer covers reuse.
__global__ __launch_bounds__(256) void scan_kernel(const short* __restrict__ gi,
                                                   const short* __restrict__ Whh,
                                                   const float* __restrict__ bias_hh,
                                                   unsigned* __restrict__ hbuf,
                                                   float* __restrict__ hmaster,
                                                   int CH, int step_base, int first) {
  int bid = blockIdx.x;
  int xcd = bid & 7, slot = bid >> 3;
  int group = xcd + 8 * (slot >> 4);
  int j = slot & 15;
  int tid = threadIdx.x;
  int w = tid >> 6, lane = tid & 63;
  int lm = lane & 15, q = lane >> 4;
  int grow = group * 16;

  __shared__ short h_lds[16 * 520];      // padded rows: 512+8
  __shared__ float gh_lds[16][100];
  __shared__ float h_loc[512];           // [16][32] fp32 master slice
  __shared__ float bhh[96];

  // W_hh slice into registers: wave w (<3) -> gate w, 2 N-tiles of 16
  bf16x8 Bf[2][16];
  if (w < 3) {
#pragma unroll
    for (int tau = 0; tau < 2; ++tau)
#pragma unroll
      for (int kt = 0; kt < 16; ++kt) {
        int row = w * 512 + j * 32 + tau * 16 + lm;
        Bf[tau][kt] = *(const bf16x8*)(Whh + (size_t)row * 512 + kt * 32 + q * 8);
      }
  }

  if (tid < 96) {
    int p = tid >> 5, cc = tid & 31;
    bhh[tid] = bias_hh[p * 512 + j * 32 + cc];
  }
#pragma unroll
  for (int u = 0; u < 2; ++u) {
    int idx = tid + u * 256;
    int r = idx >> 5, cc = idx & 31;
    h_loc[idx] = first ? 0.0f : hmaster[(size_t)(grow + r) * 512 + j * 32 + cc];
  }
  __syncthreads();

  // per-thread gi pointers (2 elements per thread per gate), bf16
  int i0 = tid, i1 = tid + 256;
  const short* gp0 = gi + (size_t)(grow + (i0 >> 5)) * G3 + j * 32 + (i0 & 31);
  const short* gp1 = gi + (size_t)(grow + (i1 >> 5)) * G3 + j * 32 + (i1 & 31);
  const size_t gstride = (size_t)256 * G3;

  // software prefetch (plain cached loads; rides across raw barriers)
  short pg0r = gp0[0], pg0z = gp0[512], pg0n = gp0[1024];
  short pg1r = gp1[0], pg1z = gp1[512], pg1n = gp1[1024];

  // poll geometry: this block reads the group's full h (16 rows x 512 cols of
  // tagged dwords = 8192 words). Thread covers 8 chunks of 16B:
  //   word f = tid*4 + c*1024  ->  row = (tid>>7) + 2c, col = (tid&127)*4
  unsigned o0 = (unsigned)tid * 16u;          // byte offset of chunk 0
  const int r0 = tid >> 7;
  const int colb = (tid & 127) * 4;
  short* lp = h_lds + r0 * 520 + colb;        // +c*1040 shorts per chunk (2 rows)
  unsigned* grp_base = hbuf + (size_t)group * 8192;

  for (int t = 0; t < CH; ++t) {
    int gstep = step_base + t;
    int p = gstep & 1;
    const unsigned* src = grp_base + (size_t)p * 131072;
    unsigned want = (unsigned)gstep;

    // ---- poll: load all 8 chunks (sc0 sc1, waitcnt INSIDE the asm so the
    // tag check can never be hoisted above the wait), retry until every word
    // of this thread's share carries tag==gstep. Bounded: wrong beats hang.
    u32x4 v0, v1, v2, v3, v4, v5, v6, v7;
    int spin = 0;
    for (;;) {
      asm volatile(
          "global_load_dwordx4 %0, %8, %16 sc0 sc1\n\t"
          "global_load_dwordx4 %1, %9, %16 sc0 sc1\n\t"
          "global_load_dwordx4 %2, %10, %16 sc0 sc1\n\t"
          "global_load_dwordx4 %3, %11, %16 sc0 sc1\n\t"
          "global_load_dwordx4 %4, %12, %16 sc0 sc1\n\t"
          "global_load_dwordx4 %5, %13, %16 sc0 sc1\n\t"
          "global_load_dwordx4 %6, %14, %16 sc0 sc1\n\t"
          "global_load_dwordx4 %7, %15, %16 sc0 sc1\n\t"
          "s_waitcnt vmcnt(0)"
          : "=&v"(v0), "=&v"(v1), "=&v"(v2), "=&v"(v3),
            "=&v"(v4), "=&v"(v5), "=&v"(v6), "=&v"(v7)
          : "v"(o0), "v"(o0 + 4096u), "v"(o0 + 8192u), "v"(o0 + 12288u),
            "v"(o0 + 16384u), "v"(o0 + 20480u), "v"(o0 + 24576u), "v"(o0 + 28672u),
            "s"(src)
          : "memory");
      unsigned d;
      d  = (v0[0] ^ want) | (v0[1] ^ want) | (v0[2] ^ want) | (v0[3] ^ want);
      d |= (v1[0] ^ want) | (v1[1] ^ want) | (v1[2] ^ want) | (v1[3] ^ want);
      d |= (v2[0] ^ want) | (v2[1] ^ want) | (v2[2] ^ want) | (v2[3] ^ want);
      d |= (v3[0] ^ want) | (v3[1] ^ want) | (v3[2] ^ want) | (v3[3] ^ want);
      d |= (v4[0] ^ want) | (v4[1] ^ want) | (v4[2] ^ want) | (v4[3] ^ want);
      d |= (v5[0] ^ want) | (v5[1] ^ want) | (v5[2] ^ want) | (v5[3] ^ want);
      d |= (v6[0] ^ want) | (v6[1] ^ want) | (v6[2] ^ want) | (v6[3] ^ want);
      d |= (v7[0] ^ want) | (v7[1] ^ want) | (v7[2] ^ want) | (v7[3] ^ want);
      if (((d & 0xffffu) == 0u) || (++spin > (1 << 16))) break;
      __builtin_amdgcn_s_sleep(1);
    }

    // stash fresh h (strip tags) straight into the MFMA staging layout
#define STASH(vv, c)                                                         \
    {                                                                        \
      s16x4 o_;                                                              \
      o_[0] = (short)(vv[0] >> 16); o_[1] = (short)(vv[1] >> 16);            \
      o_[2] = (short)(vv[2] >> 16); o_[3] = (short)(vv[3] >> 16);            \
      *(s16x4*)(lp + (c) * 1040) = o_;                                       \
    }
    STASH(v0, 0) STASH(v1, 1) STASH(v2, 2) STASH(v3, 3)
    STASH(v4, 4) STASH(v5, 5) STASH(v6, 6) STASH(v7, 7)
#undef STASH

    // consume current gi prefetch; issue next step's (rides across barriers)
    float cg0r = bs2f(pg0r), cg0z = bs2f(pg0z), cg0n = bs2f(pg0n);
    float cg1r = bs2f(pg1r), cg1z = bs2f(pg1z), cg1n = bs2f(pg1n);
    {
      size_t o = (size_t)((t + 1 < CH) ? (t + 1) : t) * gstride;
      pg0r = gp0[o]; pg0z = gp0[o + 512]; pg0n = gp0[o + 1024];
      pg1r = gp1[o]; pg1z = gp1[o + 512]; pg1n = gp1[o + 1024];
    }
    // raw barrier #1: LDS ordering only (h_lds stash -> MFMA reads);
    // no vmcnt drain, so gi prefetch + publish stores ride across.
    asm volatile("s_waitcnt lgkmcnt(0)\n\ts_barrier" ::: "memory");
    __builtin_amdgcn_sched_barrier(0);

    // MFMA: gh[16 x 32] for this wave's gate; 4 independent acc chains
    if (w < 3) {
      f32x4 a0 = {0.f,0.f,0.f,0.f}, a1 = {0.f,0.f,0.f,0.f};
      f32x4 a2 = {0.f,0.f,0.f,0.f}, a3 = {0.f,0.f,0.f,0.f};
#pragma unroll
      for (int kt = 0; kt < 8; ++kt) {
        bf16x8 a = *(const bf16x8*)(h_lds + lm * 520 + kt * 32 + q * 8);
        a0 = __builtin_amdgcn_mfma_f32_16x16x32_bf16(a, Bf[0][kt], a0, 0, 0, 0);
        a1 = __builtin_amdgcn_mfma_f32_16x16x32_bf16(a, Bf[1][kt], a1, 0, 0, 0);
      }
#pragma unroll
      for (int kt = 8; kt < 16; ++kt) {
        bf16x8 a = *(const bf16x8*)(h_lds + lm * 520 + kt * 32 + q * 8);
        a2 = __builtin_amdgcn_mfma_f32_16x16x32_bf16(a, Bf[0][kt], a2, 0, 0, 0);
        a3 = __builtin_amdgcn_mfma_f32_16x16x32_bf16(a, Bf[1][kt], a3, 0, 0, 0);
      }
#pragma unroll
      for (int r = 0; r < 4; ++r) {
        gh_lds[q * 4 + r][w * 32 + lm]      = a0[r] + a2[r];
        gh_lds[q * 4 + r][w * 32 + 16 + lm] = a1[r] + a3[r];
      }
    }
    // raw barrier #2: LDS ordering only (gh_lds writes -> cell reads)
    asm volatile("s_waitcnt lgkmcnt(0)\n\ts_barrier" ::: "memory");
    __builtin_amdgcn_sched_barrier(0);

    // elementwise GRU cell + immediate tagged publish (own values only —
    // h_lds/gh_lds hazards are covered by the barriers bracketing the next
    // iteration's phases)
    unsigned tagp = (unsigned)(gstep + 1);
    unsigned* dstb = grp_base + (size_t)(1 - p) * 131072;
    {
      int r = i0 >> 5, cc = i0 & 31;
      float hr = gh_lds[r][cc]      + bhh[cc];
      float hz = gh_lds[r][32 + cc] + bhh[32 + cc];
      float hn = gh_lds[r][64 + cc] + bhh[64 + cc];
      float rr = sigmoid_f(cg0r + hr);
      float zz = sigmoid_f(cg0z + hz);
      float nn = tanh_f(cg0n + rr * hn);
      float hv = (1.0f - zz) * nn + zz * h_loc[i0];
      h_loc[i0] = hv;
      unsigned val = (((unsigned)(unsigned short)f2bs(hv)) << 16) | tagp;
      unsigned* dp = dstb + r * 512 + j * 32 + cc;
      asm volatile("global_store_dword %0, %1, off sc0 sc1" :: "v"(dp), "v"(val) : "memory");
    }
    {
      int r = i1 >> 5, cc = i1 & 31;
      float hr = gh_lds[r][cc]      + bhh[cc];
      float hz = gh_lds[r][32 + cc] + bhh[32 + cc];
      float hn = gh_lds[r][64 + cc] + bhh[64 + cc];
      float rr = sigmoid_f(cg1r + hr);
      float zz = sigmoid_f(cg1z + hz);
      float nn = tanh_f(cg1n + rr * hn);
      float hv = (1.0f - zz) * nn + zz * h_loc[i1];
      h_loc[i1] = hv;
      unsigned val = (((unsigned)(unsigned short)f2bs(hv)) << 16) | tagp;
      unsigned* dp = dstb + r * 512 + j * 32 + cc;
      asm volatile("global_store_dword %0, %1, off sc0 sc1" :: "v"(dp), "v"(val) : "memory");
    }
  }

  // write fp32 state back (d_out doubles as h_master across chunk launches)
#pragma unroll
  for (int u = 0; u < 2; ++u) {
    int idx = tid + u * 256;
    int r = idx >> 5, cc = idx & 31;
    hmaster[(size_t)(grow + r) * 512 + j * 32 + cc] = h_loc[idx];
  }
}

// ---------------- host ----------------
extern "C" void kernel_launch(void* const* d_in, const int* in_sizes, int n_in,
                              void* d_out, int out_size, void* d_ws, size_t ws_size,
                              hipStream_t stream) {
  const float* x   = (const float*)d_in[0];
  const float* Wih = (const float*)d_in[1];
  const float* Whh = (const float*)d_in[2];
  const float* bih = (const float*)d_in[3];
  const float* bhh = (const float*)d_in[4];
  float* out = (float*)d_out;
  char* ws = (char*)d_ws;

  const size_t XT_BYTES   = (size_t)256 * 256 * 512 * 2;  // 64 MiB
  const size_t W_BYTES    = (size_t)1536 * 512 * 2;       // 1.5 MiB
  const size_t HBUF_BYTES = (size_t)2 * 256 * 512 * 4;    // 1 MiB (tagged dwords)
  const size_t FIXED = XT_BYTES + 2 * W_BYTES + HBUF_BYTES + 4096;

  int CH = 256;
  while (CH > 4 && FIXED + (size_t)CH * 256 * G3 * 2 > ws_size) CH >>= 1;

  size_t off = 0;
  short* gi = (short*)(ws + off);          off += (size_t)CH * 256 * G3 * 2;
  short* xT = (short*)(ws + off);          off += XT_BYTES;
  short* WihB = (short*)(ws + off);        off += W_BYTES;
  short* WhhB = (short*)(ws + off);        off += W_BYTES;
  unsigned* hbuf = (unsigned*)(ws + off);

  hipMemsetAsync(hbuf, 0, HBUF_BYTES, stream);

  convert_kernel<<<768, 256, 0, stream>>>(Wih, WihB, 196608);
  convert_kernel<<<768, 256, 0, stream>>>(Whh, WhhB, 196608);
  transpose_kernel<<<32768, 256, 0, stream>>>(x, xT);

  int nch = 256 / CH;
  for (int c = 0; c < nch; ++c) {
    int M = CH * 256;
    phase1_kernel<<<(M / 128) * 12, 256, 0, stream>>>(
        xT + (size_t)c * CH * 256 * 512, WihB, bih, gi, M);
    scan_kernel<<<256, 256, 0, stream>>>(gi, WhhB, bhh, hbuf, out,
                                         CH, c * CH, c == 0 ? 1 : 0);
  }
}